// Round 11
// baseline (97.352 us; speedup 1.0000x reference)
//
#include <hip/hip_runtime.h>

// Problem constants: B=4, L=512, D=128, C=128
#define NB 4
#define SL 512
#define DD 128
#define CC 128

__device__ __forceinline__ float fexp2(float x) { return __builtin_amdgcn_exp2f(x); }
__device__ __forceinline__ float frcp(float x)  { return __builtin_amdgcn_rcpf(x); }

// Kernel 1: KEY-side projection only (query side is fused into attn):
//   F [B, C, L] = exp2( K2 * (inps @ wei_x) )^T
// 512 blocks x 256 threads, 4 rows/block (threads 0-127: rows 0,1;
// threads 128-255: rows 2,3). Input rows uniform per half -> s_load.
__global__ __launch_bounds__(256) void projF_kernel(
    const float* __restrict__ inps, const float* __restrict__ wei_x,
    float* __restrict__ F)
{
    const float K2 = 2.8853900817779268f;  // 2*log2(e)
    const int row0 = blockIdx.x * 4;       // global row = b*SL + i
    const int b    = row0 >> 9;
    const int i0   = row0 & 511;
    const int c    = threadIdx.x & 127;
    const int sel  = threadIdx.x >> 7;     // wave-uniform row pair select

    const float* r0 = inps + (size_t)(row0 + 2 * sel) * DD;  // uniform -> s_load
    const float* r1 = r0 + DD;

    float a0 = 0.f, a1 = 0.f;
    #pragma unroll 8
    for (int k = 0; k < DD; ++k) {
        float w = wei_x[k * CC + c];       // coalesced across c
        a0 = fmaf(r0[k], w, a0);
        a1 = fmaf(r1[k], w, a1);
    }
    float2 v = {fexp2(K2 * a0), fexp2(K2 * a1)};
    *reinterpret_cast<float2*>(&F[((size_t)b * CC + c) * SL + i0 + 2 * sel]) = v;
}

// Kernel 2: one block per (b, 4 rows of i). 512 blocks x 1024 threads
// = 2 blocks/CU = 32 waves/CU = 8 waves/SIMD.
// Phase A now computes the 4 query-side E rows IN-BLOCK (4x128 dots of 128,
// ~0.3 us on threads that would otherwise idle; inps rows 2-wave-uniform ->
// s_load, wei_t coalesced) — removes half of the old proj kernel plus the
// E store/reload through L2.
// Phase B: jt = tid&255 -> j pair (float2 F loads); cq = tid>>8 -> 32-c
// quarter. Rational pairing: wa0/u0 + wa1/u1 = (wa0*u1+wa1*u0)/(u0*u1),
// one v_rcp per two c-terms (u = E*F+1 <= ~2^35, den <= 2^70: fp32-safe;
// 4-way pairing rejected — den could hit 2^140).
// Softmax max-pass dropped (scores bounded, sum >= 1 -> +eps matches
// reference to <= 1e-7 relative).
__global__ __launch_bounds__(1024, 8) void attn_kernel(
    const float* __restrict__ inps, const float* __restrict__ wei_a,
    const float* __restrict__ wei_t, const float* __restrict__ bxh,
    const float* __restrict__ F, float* __restrict__ out)
{
    __shared__ float4 upk[CC];             // E quads {E[i0..i0+3, c]}  (2 KB)
    __shared__ float pool[4 * 16 * DD];    // 32 KB: c-merge (B/C), then phase-D partials
    __shared__ float scT[SL * 4];          // a[i][j] stored [j][4]      (8 KB)
    __shared__ float redw[4 * 4];          // 4 rows x 4 lower-quarter waves

    const int blk = blockIdx.x;            // 512 blocks
    const int b   = blk >> 7;
    const int i0  = (blk & 127) * 4;
    const int bi0 = b * SL + i0;
    const int tid = threadIdx.x;
    const int jt  = tid & 255;             // j-pair index
    const int cq  = tid >> 8;              // c-quarter (wave-uniform)
    const int j0  = jt * 2;

    // Phase A: fused query-side projection. tid<512: i = tid>>7, c = tid&127.
    if (tid < 512) {
        const int ii = tid >> 7, c = tid & 127;
        const float K2 = 2.8853900817779268f;
        const float* r = inps + (size_t)(bi0 + ii) * DD;   // uniform -> s_load
        float acc = 0.f;
        #pragma unroll 8
        for (int k = 0; k < DD; ++k)
            acc = fmaf(r[k], wei_t[k * CC + c], acc);      // coalesced across c
        reinterpret_cast<float*>(&upk[c])[ii] = fexp2(K2 * (acc + bxh[c]));
    }
    __syncthreads();                       // barrier 1

    // Phase B: partial s over this thread's 32-c quarter, 4 i's x 2 j's.
    const int c0 = cq * 32;
    const float* fb = F + ((size_t)b * CC + c0) * SL + j0;
    const float4* up = upk + c0;
    const float* wa = wei_a + c0;          // uniform -> s_load (K$ hot)
    float sx[4] = {0.f, 0.f, 0.f, 0.f};
    float sy[4] = {0.f, 0.f, 0.f, 0.f};
    #pragma unroll 4
    for (int cp = 0; cp < 16; ++cp) {
        float2 f0 = *reinterpret_cast<const float2*>(&fb[(size_t)(2 * cp) * SL]);
        float2 f1 = *reinterpret_cast<const float2*>(&fb[(size_t)(2 * cp + 1) * SL]);
        float4 u0 = up[2 * cp];            // broadcast ds_read_b128
        float4 u1 = up[2 * cp + 1];
        float wa0 = wa[2 * cp], wa1 = wa[2 * cp + 1];
        const float* u0p = reinterpret_cast<const float*>(&u0);
        const float* u1p = reinterpret_cast<const float*>(&u1);
        #pragma unroll
        for (int i = 0; i < 4; ++i) {
            float ax = fmaf(u0p[i], f0.x, 1.0f);
            float bx = fmaf(u1p[i], f1.x, 1.0f);
            float numx = fmaf(wa0, bx, wa1 * ax);
            sx[i] = fmaf(numx, frcp(ax * bx), sx[i]);
            float ay = fmaf(u0p[i], f0.y, 1.0f);
            float by = fmaf(u1p[i], f1.y, 1.0f);
            float numy = fmaf(wa0, by, wa1 * ay);
            sy[i] = fmaf(numy, frcp(ay * by), sy[i]);
        }
    }

    // Merge c-quarters 1..3 through the pool (stride 9: gcd(9,32)=1 -> 2-way
    // max per bank = free per m136). Segment stride 2304 = 256*9.
    if (cq > 0) {
        float* m = &pool[(cq - 1) * 2304 + jt * 9];
        #pragma unroll
        for (int i = 0; i < 4; ++i) { m[i] = sx[i]; m[4 + i] = sy[i]; }
    }
    __syncthreads();                       // barrier 2

    // Phase C (threads of quarter 0, 4 waves): merge + exp + row-sum + norm.
    if (cq == 0) {
        #pragma unroll
        for (int seg = 0; seg < 3; ++seg) {
            const float* m = &pool[seg * 2304 + jt * 9];
            #pragma unroll
            for (int i = 0; i < 4; ++i) { sx[i] += m[i]; sy[i] += m[4 + i]; }
        }
        const float KE = -2.8853900817779268f;  // -2*log2(e)
        float ex[4], ey[4];
        const int lane = tid & 63, wv = tid >> 6;   // wv in 0..3
        #pragma unroll
        for (int i = 0; i < 4; ++i) {
            ex[i] = fexp2(sx[i] * KE);
            ey[i] = fexp2(sy[i] * KE);
            float t = ex[i] + ey[i];
            #pragma unroll
            for (int off = 32; off > 0; off >>= 1)
                t += __shfl_xor(t, off, 64);
            if (lane == 0) redw[i * 4 + wv] = t;
        }
        __syncthreads();                   // barrier 3
        float4 av0, av1;
        {
            float S0 = redw[0] + redw[1] + redw[2] + redw[3];
            float S1 = redw[4] + redw[5] + redw[6] + redw[7];
            float S2 = redw[8] + redw[9] + redw[10] + redw[11];
            float S3 = redw[12] + redw[13] + redw[14] + redw[15];
            float r0 = frcp(S0 + 1e-7f), r1 = frcp(S1 + 1e-7f);
            float r2 = frcp(S2 + 1e-7f), r3 = frcp(S3 + 1e-7f);
            av0 = make_float4(ex[0] * r0, ex[1] * r1, ex[2] * r2, ex[3] * r3);
            av1 = make_float4(ey[0] * r0, ey[1] * r1, ey[2] * r2, ey[3] * r3);
        }
        *reinterpret_cast<float4*>(&scT[j0 * 4])     = av0;  // a[*][j0]
        *reinterpret_cast<float4*>(&scT[j0 * 4 + 4]) = av1;  // a[*][j0+1]
    } else {
        __syncthreads();                   // barrier 3 (match)
    }
    __syncthreads();                       // barrier 4: scT ready, pool free

    // Phase D (tid < 512 — each inps float4 feeds 4 rows; upper 8 waves wait
    // at the barrier, consuming no issue slots).
    if (tid < 512) {
        const int dq = (tid & 31) * 4;
        const int jq = tid >> 5;           // 0..15, 32 j each
        const float* ibase = inps + (size_t)b * SL * DD;
        float4 acc0 = {0,0,0,0}, acc1 = {0,0,0,0}, acc2 = {0,0,0,0}, acc3 = {0,0,0,0};
        const int jb = jq * 32;
        #pragma unroll 4
        for (int jj = 0; jj < 32; ++jj) {
            int jx = jb + jj;
            float4 v  = *reinterpret_cast<const float4*>(ibase + (size_t)jx * DD + dq);
            float4 a4 = *reinterpret_cast<const float4*>(&scT[jx * 4]);  // broadcast
            acc0.x = fmaf(a4.x, v.x, acc0.x); acc0.y = fmaf(a4.x, v.y, acc0.y);
            acc0.z = fmaf(a4.x, v.z, acc0.z); acc0.w = fmaf(a4.x, v.w, acc0.w);
            acc1.x = fmaf(a4.y, v.x, acc1.x); acc1.y = fmaf(a4.y, v.y, acc1.y);
            acc1.z = fmaf(a4.y, v.z, acc1.z); acc1.w = fmaf(a4.y, v.w, acc1.w);
            acc2.x = fmaf(a4.z, v.x, acc2.x); acc2.y = fmaf(a4.z, v.y, acc2.y);
            acc2.z = fmaf(a4.z, v.z, acc2.z); acc2.w = fmaf(a4.z, v.w, acc2.w);
            acc3.x = fmaf(a4.w, v.x, acc3.x); acc3.y = fmaf(a4.w, v.y, acc3.y);
            acc3.z = fmaf(a4.w, v.z, acc3.z); acc3.w = fmaf(a4.w, v.w, acc3.w);
        }
        *reinterpret_cast<float4*>(&pool[(0 * 16 + jq) * DD + dq]) = acc0;
        *reinterpret_cast<float4*>(&pool[(1 * 16 + jq) * DD + dq]) = acc1;
        *reinterpret_cast<float4*>(&pool[(2 * 16 + jq) * DD + dq]) = acc2;
        *reinterpret_cast<float4*>(&pool[(3 * 16 + jq) * DD + dq]) = acc3;
    }
    __syncthreads();                       // barrier 5
    if (tid < 512) {
        int i = tid >> 7, d = tid & 127;   // 4 rows x 128 d
        float sum = 0.f;
        #pragma unroll
        for (int q = 0; q < 16; ++q) sum += pool[(i * 16 + q) * DD + d];
        out[(size_t)(bi0 + i) * DD + d] = sum;
    }
}

extern "C" void kernel_launch(void* const* d_in, const int* in_sizes, int n_in,
                              void* d_out, int out_size, void* d_ws, size_t ws_size,
                              hipStream_t stream) {
    const float* inps  = (const float*)d_in[0];  // [B, L, D]
    const float* wei_t = (const float*)d_in[1];  // [D, C]
    const float* wei_x = (const float*)d_in[2];  // [D, C]
    const float* bxh   = (const float*)d_in[3];  // [C]
    const float* wei_a = (const float*)d_in[4];  // [C]
    // d_in[5] = bxa (scalar): uniform shift before softmax -> dropped.
    float* out = (float*)d_out;                  // [B, L, D] fp32

    float* F = (float*)d_ws;                     // [B, C, L]  1 MB

    projF_kernel<<<NB * SL / 4, 256, 0, stream>>>(inps, wei_x, F);
    attn_kernel<<<NB * SL / 4, 1024, 0, stream>>>(inps, wei_a, wei_t, bxh, F, out);
}

// Round 12
// 92.123 us; speedup vs baseline: 1.0568x; 1.0568x over previous
//
#include <hip/hip_runtime.h>

// Problem constants: B=4, L=512, D=128, C=128
#define NB 4
#define SL 512
#define DD 128
#define CC 128

__device__ __forceinline__ float fexp2(float x) { return __builtin_amdgcn_exp2f(x); }
__device__ __forceinline__ float frcp(float x)  { return __builtin_amdgcn_rcpf(x); }

// ROUND 12 = revert to round 10 (best: 90.2 us). Round 11's fused E-proj
// regressed -7 us: single serial fma chain on the critical path ahead of
// phase B in every block + per-block wei_t re-stream. Separate proj wins.

// Kernel 1: projections, EXPONENTIATED (trans factorization):
//   E  [B*L, C]  = exp2( K2 * (inps @ wei_t + bxh) )
//   F  [B, C, L] = exp2( K2 * (inps @ wei_x) )^T
__global__ __launch_bounds__(256) void proj_kernel(
    const float* __restrict__ inps, const float* __restrict__ wei_t,
    const float* __restrict__ wei_x, const float* __restrict__ bxh,
    float* __restrict__ E, float* __restrict__ F)
{
    const float K2 = 2.8853900817779268f;  // 2*log2(e)
    const int row0 = blockIdx.x * 2;       // global row = b*SL + i
    const int b    = row0 >> 9;
    const int i0   = row0 & 511;
    const int c    = threadIdx.x & 127;
    const int sel  = threadIdx.x >> 7;     // wave-uniform: waves 0-1 wei_t, 2-3 wei_x

    const float* W  = sel ? wei_x : wei_t;
    const float* r0 = inps + (size_t)row0 * DD;   // uniform -> s_load
    const float* r1 = r0 + DD;

    float a0 = 0.f, a1 = 0.f;
    #pragma unroll 8
    for (int k = 0; k < DD; ++k) {
        float w = W[k * CC + c];           // coalesced across c
        a0 = fmaf(r0[k], w, a0);
        a1 = fmaf(r1[k], w, a1);
    }

    if (sel == 0) {
        float bb = bxh[c];
        E[(size_t)(row0 + 0) * CC + c] = fexp2(K2 * (a0 + bb));
        E[(size_t)(row0 + 1) * CC + c] = fexp2(K2 * (a1 + bb));
    } else {
        float2 v = {fexp2(K2 * a0), fexp2(K2 * a1)};
        *reinterpret_cast<float2*>(&F[((size_t)b * CC + c) * SL + i0]) = v;
    }
}

// Kernel 2: one block per (b, 4 rows of i). 512 blocks x 1024 threads
// = 2 blocks/CU = 32 waves/CU = 8 waves/SIMD.
// Phase B: jt = tid&255 -> j pair (float2 F loads); cq = tid>>8 -> 32-c
// quarter. Rational pairing: wa0/u0 + wa1/u1 = (wa0*u1+wa1*u0)/(u0*u1),
// one v_rcp per two c-terms (u = E*F+1 <= ~2^35, den <= 2^70: fp32-safe).
// c-quarter partials merge through a 32 KB LDS pool (stride 9 ->
// conflict-free) that phase D later reuses for partials.
// Softmax max-pass dropped (scores bounded, sum >= 1 -> +eps matches
// reference to <= 1e-7 relative).
__global__ __launch_bounds__(1024, 8) void attn_kernel(
    const float* __restrict__ inps, const float* __restrict__ wei_a,
    const float* __restrict__ E, const float* __restrict__ F,
    float* __restrict__ out)
{
    __shared__ float4 upk[CC];             // E quads {E[i0..i0+3, c]}  (2 KB)
    __shared__ float pool[4 * 16 * DD];    // 32 KB: c-merge (B/C), then phase-D partials
    __shared__ float scT[SL * 4];          // a[i][j] stored [j][4]      (8 KB)
    __shared__ float redw[4 * 4];          // 4 rows x 4 lower-quarter waves

    const int blk = blockIdx.x;            // 512 blocks
    const int b   = blk >> 7;
    const int i0  = (blk & 127) * 4;
    const int bi0 = b * SL + i0;
    const int tid = threadIdx.x;
    const int jt  = tid & 255;             // j-pair index
    const int cq  = tid >> 8;              // c-quarter (wave-uniform)
    const int j0  = jt * 2;

    // Phase A: stage the four block-uniform E rows as quads (128 threads)
    if (tid < CC) {
        float4 u;
        u.x = E[(size_t)(bi0 + 0) * CC + tid];
        u.y = E[(size_t)(bi0 + 1) * CC + tid];
        u.z = E[(size_t)(bi0 + 2) * CC + tid];
        u.w = E[(size_t)(bi0 + 3) * CC + tid];
        upk[tid] = u;
    }
    __syncthreads();                       // barrier 1

    // Phase B: partial s over this thread's 32-c quarter, 4 i's x 2 j's.
    const int c0 = cq * 32;
    const float* fb = F + ((size_t)b * CC + c0) * SL + j0;
    const float4* up = upk + c0;
    const float* wa = wei_a + c0;          // uniform -> s_load (K$ hot)
    float sx[4] = {0.f, 0.f, 0.f, 0.f};
    float sy[4] = {0.f, 0.f, 0.f, 0.f};
    #pragma unroll 4
    for (int cp = 0; cp < 16; ++cp) {
        float2 f0 = *reinterpret_cast<const float2*>(&fb[(size_t)(2 * cp) * SL]);
        float2 f1 = *reinterpret_cast<const float2*>(&fb[(size_t)(2 * cp + 1) * SL]);
        float4 u0 = up[2 * cp];            // broadcast ds_read_b128
        float4 u1 = up[2 * cp + 1];
        float wa0 = wa[2 * cp], wa1 = wa[2 * cp + 1];
        const float* u0p = reinterpret_cast<const float*>(&u0);
        const float* u1p = reinterpret_cast<const float*>(&u1);
        #pragma unroll
        for (int i = 0; i < 4; ++i) {
            float ax = fmaf(u0p[i], f0.x, 1.0f);
            float bx = fmaf(u1p[i], f1.x, 1.0f);
            float numx = fmaf(wa0, bx, wa1 * ax);
            sx[i] = fmaf(numx, frcp(ax * bx), sx[i]);
            float ay = fmaf(u0p[i], f0.y, 1.0f);
            float by = fmaf(u1p[i], f1.y, 1.0f);
            float numy = fmaf(wa0, by, wa1 * ay);
            sy[i] = fmaf(numy, frcp(ay * by), sy[i]);
        }
    }

    // Merge c-quarters 1..3 through the pool (stride 9: gcd(9,32)=1 -> 2-way
    // max per bank = free per m136). Segment stride 2304 = 256*9.
    if (cq > 0) {
        float* m = &pool[(cq - 1) * 2304 + jt * 9];
        #pragma unroll
        for (int i = 0; i < 4; ++i) { m[i] = sx[i]; m[4 + i] = sy[i]; }
    }
    __syncthreads();                       // barrier 2

    // Phase C (threads of quarter 0, 4 waves): merge + exp + row-sum + norm.
    if (cq == 0) {
        #pragma unroll
        for (int seg = 0; seg < 3; ++seg) {
            const float* m = &pool[seg * 2304 + jt * 9];
            #pragma unroll
            for (int i = 0; i < 4; ++i) { sx[i] += m[i]; sy[i] += m[4 + i]; }
        }
        const float KE = -2.8853900817779268f;  // -2*log2(e)
        float ex[4], ey[4];
        const int lane = tid & 63, wv = tid >> 6;   // wv in 0..3
        #pragma unroll
        for (int i = 0; i < 4; ++i) {
            ex[i] = fexp2(sx[i] * KE);
            ey[i] = fexp2(sy[i] * KE);
            float t = ex[i] + ey[i];
            #pragma unroll
            for (int off = 32; off > 0; off >>= 1)
                t += __shfl_xor(t, off, 64);
            if (lane == 0) redw[i * 4 + wv] = t;
        }
        __syncthreads();                   // barrier 3
        float4 av0, av1;
        {
            float S0 = redw[0] + redw[1] + redw[2] + redw[3];
            float S1 = redw[4] + redw[5] + redw[6] + redw[7];
            float S2 = redw[8] + redw[9] + redw[10] + redw[11];
            float S3 = redw[12] + redw[13] + redw[14] + redw[15];
            float r0 = frcp(S0 + 1e-7f), r1 = frcp(S1 + 1e-7f);
            float r2 = frcp(S2 + 1e-7f), r3 = frcp(S3 + 1e-7f);
            av0 = make_float4(ex[0] * r0, ex[1] * r1, ex[2] * r2, ex[3] * r3);
            av1 = make_float4(ey[0] * r0, ey[1] * r1, ey[2] * r2, ey[3] * r3);
        }
        *reinterpret_cast<float4*>(&scT[j0 * 4])     = av0;  // a[*][j0]
        *reinterpret_cast<float4*>(&scT[j0 * 4 + 4]) = av1;  // a[*][j0+1]
    } else {
        __syncthreads();                   // barrier 3 (match)
    }
    __syncthreads();                       // barrier 4: scT ready, pool free

    // Phase D (tid < 512 — each inps float4 feeds 4 rows; upper 8 waves wait
    // at the barrier, consuming no issue slots).
    if (tid < 512) {
        const int dq = (tid & 31) * 4;
        const int jq = tid >> 5;           // 0..15, 32 j each
        const float* ibase = inps + (size_t)b * SL * DD;
        float4 acc0 = {0,0,0,0}, acc1 = {0,0,0,0}, acc2 = {0,0,0,0}, acc3 = {0,0,0,0};
        const int jb = jq * 32;
        #pragma unroll 4
        for (int jj = 0; jj < 32; ++jj) {
            int jx = jb + jj;
            float4 v  = *reinterpret_cast<const float4*>(ibase + (size_t)jx * DD + dq);
            float4 a4 = *reinterpret_cast<const float4*>(&scT[jx * 4]);  // broadcast
            acc0.x = fmaf(a4.x, v.x, acc0.x); acc0.y = fmaf(a4.x, v.y, acc0.y);
            acc0.z = fmaf(a4.x, v.z, acc0.z); acc0.w = fmaf(a4.x, v.w, acc0.w);
            acc1.x = fmaf(a4.y, v.x, acc1.x); acc1.y = fmaf(a4.y, v.y, acc1.y);
            acc1.z = fmaf(a4.y, v.z, acc1.z); acc1.w = fmaf(a4.y, v.w, acc1.w);
            acc2.x = fmaf(a4.z, v.x, acc2.x); acc2.y = fmaf(a4.z, v.y, acc2.y);
            acc2.z = fmaf(a4.z, v.z, acc2.z); acc2.w = fmaf(a4.z, v.w, acc2.w);
            acc3.x = fmaf(a4.w, v.x, acc3.x); acc3.y = fmaf(a4.w, v.y, acc3.y);
            acc3.z = fmaf(a4.w, v.z, acc3.z); acc3.w = fmaf(a4.w, v.w, acc3.w);
        }
        *reinterpret_cast<float4*>(&pool[(0 * 16 + jq) * DD + dq]) = acc0;
        *reinterpret_cast<float4*>(&pool[(1 * 16 + jq) * DD + dq]) = acc1;
        *reinterpret_cast<float4*>(&pool[(2 * 16 + jq) * DD + dq]) = acc2;
        *reinterpret_cast<float4*>(&pool[(3 * 16 + jq) * DD + dq]) = acc3;
    }
    __syncthreads();                       // barrier 5
    if (tid < 512) {
        int i = tid >> 7, d = tid & 127;   // 4 rows x 128 d
        float sum = 0.f;
        #pragma unroll
        for (int q = 0; q < 16; ++q) sum += pool[(i * 16 + q) * DD + d];
        out[(size_t)(bi0 + i) * DD + d] = sum;
    }
}

extern "C" void kernel_launch(void* const* d_in, const int* in_sizes, int n_in,
                              void* d_out, int out_size, void* d_ws, size_t ws_size,
                              hipStream_t stream) {
    const float* inps  = (const float*)d_in[0];  // [B, L, D]
    const float* wei_t = (const float*)d_in[1];  // [D, C]
    const float* wei_x = (const float*)d_in[2];  // [D, C]
    const float* bxh   = (const float*)d_in[3];  // [C]
    const float* wei_a = (const float*)d_in[4];  // [C]
    // d_in[5] = bxa (scalar): uniform shift before softmax -> dropped.
    float* out = (float*)d_out;                  // [B, L, D] fp32

    float* E = (float*)d_ws;                     // [B*L, C]   1 MB
    float* F = E + (size_t)NB * SL * CC;         // [B, C, L]  1 MB

    proj_kernel<<<NB * SL / 2, 256, 0, stream>>>(inps, wei_t, wei_x, bxh, E, F);
    attn_kernel<<<NB * SL / 4, 1024, 0, stream>>>(inps, wei_a, E, F, out);
}